// Round 5
// baseline (72.144 us; speedup 1.0000x reference)
//
#include <hip/hip_runtime.h>
#include <math.h>

// Quanvolution: 8192 images of 28x28 -> 14x14 grid of 2x2 patches, each patch
// drives a 4-qubit real-amplitude circuit; output <Z_w> -> (8192, 784) f32.
//
// R5 = R4 (packed v2f circuit, folded layer-0, Taylor half-angle trig,
// setup kernel for param sincos) + a DIAGNOSTIC dispatch: the same kernel
// with REPS=8 accumulating perturbed evaluations into d_ws. Its only purpose
// is to run long enough (>45us) to appear in the rocprof top-5 so we can
// finally read VALUBusy/Occupancy/VGPR/FETCH for our code. Output path is
// unchanged and correct; the diag write goes to scratch.

#define N_PAIRS (8192 * 98)   // 98 patch-pairs per image; 3136 blocks of 256 exact

typedef float v2f __attribute__((ext_vector_type(2)));

static __device__ __forceinline__ v2f splat(float v) { v2f r; r.x = v; r.y = v; return r; }
static __device__ __forceinline__ v2f vfma(v2f a, v2f b, v2f c) {
    return __builtin_elementwise_fma(a, b, c);
}

__global__ void setup_params_kernel(const float* __restrict__ params,
                                    float* __restrict__ ws) {
    int i = threadIdx.x;
    if (i < 8) {
        float s, c;
        sincosf(params[i] * 0.5f, &s, &c);
        ws[i]     = c;   // ws[0..3]=cos(p0w/2), ws[4..7]=cos(p1w/2)
        ws[i + 8] = s;   // ws[8..11]=sin(p0w/2), ws[12..15]=sin(p1w/2)
    }
}

static __device__ __forceinline__ void half_trig2(v2f x, v2f& c, v2f& s) {
    // sin/cos of x/2 for x in [0,1): h in [0,0.5), 3-term Taylor, err < 2e-9.
    v2f h  = x * splat(0.5f);
    v2f h2 = h * h;
    s = h * vfma(h2, vfma(h2, splat(8.3333338e-3f), splat(-1.6666667e-1f)), splat(1.0f));
    c = vfma(h2, vfma(h2, vfma(h2, splat(-1.3888889e-3f), splat(4.1666668e-2f)),
                      splat(-0.5f)), splat(1.0f));
}

static __device__ __forceinline__ void cnot_ring(v2f* a) {
#pragma unroll
    for (int w = 0; w < 4; ++w) {
        const int cs = 8 >> w;
        const int ts = 8 >> ((w + 1) & 3);
#pragma unroll
        for (int i = 0; i < 16; ++i) {
            if (!(i & cs)) continue;
            if (i & ts) continue;
            v2f tmp = a[i];
            a[i] = a[i | ts];
            a[i | ts] = tmp;
        }
    }
}

// Full circuit for a packed pair of patches; returns z0..z3 packed.
static __device__ __forceinline__ void circuit(
    v2f x0, v2f x1, v2f x2, v2f x3, const float* __restrict__ ws,
    v2f& z0, v2f& z1, v2f& z2, v2f& z3)
{
    v2f c0, s0, c1, s1, c2, s2, c3, s3, cx, sx, pc, ps;
    half_trig2(x0, cx, sx); pc = splat(ws[0]); ps = splat(ws[8]);
    c0 = cx * pc - sx * ps; s0 = sx * pc + cx * ps;
    half_trig2(x1, cx, sx); pc = splat(ws[1]); ps = splat(ws[9]);
    c1 = cx * pc - sx * ps; s1 = sx * pc + cx * ps;
    half_trig2(x2, cx, sx); pc = splat(ws[2]); ps = splat(ws[10]);
    c2 = cx * pc - sx * ps; s2 = sx * pc + cx * ps;
    half_trig2(x3, cx, sx); pc = splat(ws[3]); ps = splat(ws[11]);
    c3 = cx * pc - sx * ps; s3 = sx * pc + cx * ps;

    v2f tt[4], uu[4];
    tt[0] = c0 * c1; tt[1] = c0 * s1; tt[2] = s0 * c1; tt[3] = s0 * s1;
    uu[0] = c2 * c3; uu[1] = c2 * s3; uu[2] = s2 * c3; uu[3] = s2 * s3;

    v2f a[16];
#pragma unroll
    for (int i = 0; i < 16; ++i)
        a[i] = tt[i >> 2] * uu[i & 3];

    cnot_ring(a);

#pragma unroll
    for (int w = 0; w < 4; ++w) {
        v2f qc = splat(ws[4 + w]);
        v2f qs = splat(ws[12 + w]);
        const int stride = 8 >> w;
#pragma unroll
        for (int i = 0; i < 16; ++i) {
            if (i & stride) continue;
            v2f v0 = a[i];
            v2f v1 = a[i + stride];
            a[i]          = qc * v0 - qs * v1;
            a[i + stride] = qs * v0 + qc * v1;
        }
    }

    cnot_ring(a);

    v2f p2[16];
#pragma unroll
    for (int i = 0; i < 16; ++i) p2[i] = a[i] * a[i];

    v2f e[8], d[8];
#pragma unroll
    for (int j = 0; j < 8; ++j) { e[j] = p2[2*j] + p2[2*j+1]; d[j] = p2[2*j] - p2[2*j+1]; }
    z3 = ((d[0] + d[1]) + (d[2] + d[3])) + ((d[4] + d[5]) + (d[6] + d[7]));

    v2f f[4], g[4];
#pragma unroll
    for (int k = 0; k < 4; ++k) { f[k] = e[2*k] + e[2*k+1]; g[k] = e[2*k] - e[2*k+1]; }
    z2 = (g[0] + g[1]) + (g[2] + g[3]);

    v2f h0 = f[0] + f[1], h1 = f[2] + f[3];
    v2f m0 = f[0] - f[1], m1 = f[2] - f[3];
    z1 = m0 + m1;
    z0 = h0 - h1;
}

template <int REPS>
__global__ __launch_bounds__(256) void quanv_kernel(
    const float* __restrict__ x,    // (8192, 28, 28)
    const float* __restrict__ ws,   // 16 precomputed param cos/sin
    float* __restrict__ o)          // (8192, 784) or scratch
{
    int t = blockIdx.x * blockDim.x + threadIdx.x;

    int b    = t / 98;
    int q    = t - b * 98;
    int r    = q / 7;
    int pcol = q - r * 7;

    const float* px = x + b * 784 + (2 * r) * 28 + 4 * pcol;
    float4 row0 = *reinterpret_cast<const float4*>(px);
    float4 row1 = *reinterpret_cast<const float4*>(px + 28);

    v2f x0; x0.x = row0.x; x0.y = row0.z;
    v2f x1; x1.x = row0.y; x1.y = row0.w;
    v2f x2; x2.x = row1.x; x2.y = row1.z;
    v2f x3; x3.x = row1.y; x3.y = row1.w;

    v2f az0 = splat(0.f), az1 = splat(0.f), az2 = splat(0.f), az3 = splat(0.f);
#pragma unroll
    for (int rep = 0; rep < REPS; ++rep) {
        // Tiny per-rep perturbation prevents CSE across reps; REPS=1 adds 0.
        v2f pert = splat((float)rep * 1e-7f);
        v2f z0, z1, z2, z3;
        circuit(x0 + pert, x1 + pert, x2 + pert, x3 + pert, ws, z0, z1, z2, z3);
        az0 += z0; az1 += z1; az2 += z2; az3 += z3;
    }

    float4* oo = reinterpret_cast<float4*>(o + (size_t)t * 8);
    oo[0] = make_float4(az0.x, az1.x, az2.x, az3.x);
    oo[1] = make_float4(az0.y, az1.y, az2.y, az3.y);
}

extern "C" void kernel_launch(void* const* d_in, const int* in_sizes, int n_in,
                              void* d_out, int out_size, void* d_ws, size_t ws_size,
                              hipStream_t stream) {
    const float* x      = (const float*)d_in[0];  // (8192,28,28) f32
    const float* params = (const float*)d_in[1];  // (2,4) f32
    float* out          = (float*)d_out;          // (8192,784) f32
    float* ws           = (float*)d_ws;           // scratch (params trig + diag sink)

    setup_params_kernel<<<1, 64, 0, stream>>>(params, ws);

    const int block = 256;
    const int grid  = N_PAIRS / block;            // 3136, exact

    // Correct output (unchanged semantics).
    quanv_kernel<1><<<grid, block, 0, stream>>>(x, ws, out);

    // DIAGNOSTIC: 8x compute, long enough to surface in rocprof top-5.
    // Writes to scratch past the 16-float param block (256B-aligned offset).
    quanv_kernel<8><<<grid, block, 0, stream>>>(x, ws, ws + 64);
}

// Round 6
// 19.845 us; speedup vs baseline: 3.6354x; 3.6354x over previous
//
#include <hip/hip_runtime.h>
#include <math.h>

// Quanvolution closed form (Heisenberg picture). For each 2x2 patch with
// pixels x0..x3 and params p0 (layer0), p1 (layer1):
//   theta_w = x_w + p0_w ; C_w = cos(theta_w), S_w = sin(theta_w)
//   c_w = cos(p1_w), s_w = sin(p1_w)
// Conjugating Z_w through [CNOT ring]·[RY(p1)]·[CNOT ring] gives 18 Pauli
// strings total; expectations on the product state are monomials in C_w,S_w:
//   z0 = A C0C1C3 + B S0S1C2S3 + D S1S2C3 + E S0
//   z1 = F C0C2C3 + G S0S2
//   z2 = H C1C3 + I C0S1S2C3 + J S0S1C2 + K S0S3
//   z3 = L C0C2 + M C1S2S3 + N C0S1S3 + O S0C1C2C3 + P C2S3 + Q C0C1S2
//        + R S0S2C3 + T S1
// Coefficients precomputed in a tiny setup kernel. Main kernel: 2 patches per
// thread packed in <2 x float>, Taylor full-angle trig (x in [0,1)).

#define N_PAIRS (8192 * 98)   // 98 patch-pairs per image; 3136 blocks of 256 exact

typedef float v2f __attribute__((ext_vector_type(2)));

static __device__ __forceinline__ v2f splat(float v) { v2f r; r.x = v; r.y = v; return r; }
static __device__ __forceinline__ v2f vfma(v2f a, v2f b, v2f c) {
    return __builtin_elementwise_fma(a, b, c);
}

__global__ void setup_params_kernel(const float* __restrict__ params,
                                    float* __restrict__ ws) {
    if (threadIdx.x == 0) {
        float cp[4], sp[4], c[4], s[4];
#pragma unroll
        for (int w = 0; w < 4; ++w) sincosf(params[w],     &sp[w], &cp[w]); // layer0
#pragma unroll
        for (int w = 0; w < 4; ++w) sincosf(params[4 + w], &s[w],  &c[w]);  // layer1
#pragma unroll
        for (int w = 0; w < 4; ++w) { ws[w] = cp[w]; ws[4 + w] = sp[w]; }
        ws[8]  =  c[1]*c[2]*c[3];        // A
        ws[9]  = -c[1]*c[2]*s[3];        // B
        ws[10] = -s[1]*c[2]*c[3];        // D
        ws[11] = -s[1]*s[2]*s[3];        // E
        ws[12] =  c[0]*c[1];             // F
        ws[13] =  s[0]*s[1];             // G
        ws[14] =  c[0]*c[1]*c[2];        // H
        ws[15] = -c[0]*s[1]*c[2];        // I
        ws[16] = -s[0]*c[1]*c[2];        // J
        ws[17] = -s[0]*s[1]*s[2];        // K
        ws[18] =  c[0]*c[1]*c[2]*c[3];   // L
        ws[19] = -c[0]*c[1]*s[2]*c[3];   // M
        ws[20] =  c[0]*s[1]*s[2]*c[3];   // N
        ws[21] = -c[0]*s[1]*s[2]*s[3];   // O
        ws[22] =  s[0]*c[1]*c[2]*s[3];   // P
        ws[23] = -s[0]*c[1]*s[2]*s[3];   // Q
        ws[24] =  s[0]*s[1]*c[2]*c[3];   // R
        ws[25] =  s[0]*s[1]*s[2]*s[3];   // T
    }
}

// cos(x), sin(x) for x in [0,1): Taylor, err < 3e-5 (way inside threshold).
static __device__ __forceinline__ void trig01(v2f x, v2f& c, v2f& s) {
    v2f u = x * x;
    v2f sp = vfma(u, vfma(u, vfma(u, splat(-1.9841270e-4f), splat(8.3333338e-3f)),
                          splat(-1.6666667e-1f)), splat(1.0f));
    s = x * sp;
    c = vfma(u, vfma(u, vfma(u, vfma(u, splat(2.4801588e-5f), splat(-1.3888889e-3f)),
                             splat(4.1666668e-2f)), splat(-0.5f)), splat(1.0f));
}

__global__ __launch_bounds__(256) void quanv_kernel(
    const float* __restrict__ x,    // (8192, 28, 28)
    const float* __restrict__ ws,   // 26 precomputed uniforms
    float* __restrict__ out)        // (8192, 784)
{
    int t = blockIdx.x * blockDim.x + threadIdx.x;

    int b    = t / 98;
    int q    = t - b * 98;        // pair index within image [0,98)
    int r    = q / 7;             // patch row [0,14)
    int pcol = q - r * 7;         // pair column [0,7)

    const float* px = x + b * 784 + (2 * r) * 28 + 4 * pcol;
    float4 row0 = *reinterpret_cast<const float4*>(px);
    float4 row1 = *reinterpret_cast<const float4*>(px + 28);

    // Packed pixel angles: .x = patch A, .y = patch B.
    v2f x0; x0.x = row0.x; x0.y = row0.z;
    v2f x1; x1.x = row0.y; x1.y = row0.w;
    v2f x2; x2.x = row1.x; x2.y = row1.z;
    v2f x3; x3.x = row1.y; x3.y = row1.w;

    // theta_w = x_w + p0_w via angle addition with uniform cos/sin(p0_w).
    v2f C0, S0, C1, S1, C2, S2, C3, S3;
    {
        v2f cx, sx, cp, sp;
        trig01(x0, cx, sx); cp = splat(ws[0]); sp = splat(ws[4]);
        C0 = cx * cp - sx * sp; S0 = sx * cp + cx * sp;
        trig01(x1, cx, sx); cp = splat(ws[1]); sp = splat(ws[5]);
        C1 = cx * cp - sx * sp; S1 = sx * cp + cx * sp;
        trig01(x2, cx, sx); cp = splat(ws[2]); sp = splat(ws[6]);
        C2 = cx * cp - sx * sp; S2 = sx * cp + cx * sp;
        trig01(x3, cx, sx); cp = splat(ws[3]); sp = splat(ws[7]);
        C3 = cx * cp - sx * sp; S3 = sx * cp + cx * sp;
    }

    // Shared pairwise products.
    v2f C0C1 = C0 * C1, C0C2 = C0 * C2, C0C3 = C0 * C3;
    v2f C1C2 = C1 * C2, C1C3 = C1 * C3, C2C3 = C2 * C3;
    v2f S0S1 = S0 * S1, S0S2 = S0 * S2, S0S3 = S0 * S3;
    v2f S1S2 = S1 * S2, S1S3 = S1 * S3, S2S3 = S2 * S3;
    v2f C2S3 = C2 * S3;

    // z0 = A C0C1C3 + B S0S1C2S3 + D S1S2C3 + E S0
    v2f z0 =            splat(ws[8])  * (C0 * C1C3);
    z0 = vfma(splat(ws[9]),  S0S1 * C2S3, z0);
    z0 = vfma(splat(ws[10]), S1S2 * C3,   z0);
    z0 = vfma(splat(ws[11]), S0,          z0);

    // z1 = F C0C2C3 + G S0S2
    v2f z1 =            splat(ws[12]) * (C0 * C2C3);
    z1 = vfma(splat(ws[13]), S0S2, z1);

    // z2 = H C1C3 + I C0S1S2C3 + J S0S1C2 + K S0S3
    v2f z2 =            splat(ws[14]) * C1C3;
    z2 = vfma(splat(ws[15]), C0C3 * S1S2, z2);
    z2 = vfma(splat(ws[16]), S0S1 * C2,   z2);
    z2 = vfma(splat(ws[17]), S0S3,        z2);

    // z3 = L C0C2 + M C1S2S3 + N C0S1S3 + O S0C1C2C3 + P C2S3 + Q C0C1S2
    //      + R S0S2C3 + T S1
    v2f z3 =            splat(ws[18]) * C0C2;
    z3 = vfma(splat(ws[19]), C1 * S2S3,        z3);
    z3 = vfma(splat(ws[20]), C0 * S1S3,        z3);
    z3 = vfma(splat(ws[21]), S0 * (C1 * C2C3), z3);
    z3 = vfma(splat(ws[22]), C2S3,             z3);
    z3 = vfma(splat(ws[23]), C0C1 * S2,        z3);
    z3 = vfma(splat(ws[24]), S0S2 * C3,        z3);
    z3 = vfma(splat(ws[25]), S1,               z3);
    (void)C1C2;

    float4* o = reinterpret_cast<float4*>(out + (size_t)t * 8);
    o[0] = make_float4(z0.x, z1.x, z2.x, z3.x);
    o[1] = make_float4(z0.y, z1.y, z2.y, z3.y);
}

extern "C" void kernel_launch(void* const* d_in, const int* in_sizes, int n_in,
                              void* d_out, int out_size, void* d_ws, size_t ws_size,
                              hipStream_t stream) {
    const float* x      = (const float*)d_in[0];  // (8192,28,28) f32
    const float* params = (const float*)d_in[1];  // (2,4) f32
    float* out          = (float*)d_out;          // (8192,784) f32
    float* ws           = (float*)d_ws;           // 26 floats used

    setup_params_kernel<<<1, 64, 0, stream>>>(params, ws);

    const int block = 256;
    const int grid  = N_PAIRS / block;            // 3136, exact
    quanv_kernel<<<grid, block, 0, stream>>>(x, ws, out);
}

// Round 7
// 14.541 us; speedup vs baseline: 4.9615x; 1.3648x over previous
//
#include <hip/hip_runtime.h>
#include <math.h>

// Quanvolution closed form (Heisenberg picture), single fused kernel.
//   theta_w = x_w + p0_w ; C_w = cos(theta_w), S_w = sin(theta_w)
//   c_w = cos(p1_w), s_w = sin(p1_w)
//   z0 = A C0C1C3 + B S0S1C2S3 + D S1S2C3 + E S0
//   z1 = F C0C2C3 + G S0S2
//   z2 = H C1C3 + I C0S1S2C3 + J S0S1C2 + K S0S3
//   z3 = L C0C2 + M C1S2S3 + N C0S1S3 + O S0C1C2C3 + P C2S3 + Q C0C1S2
//        + R S0S2C3 + T S1
// R7: no setup dispatch (params trig per-thread, readfirstlane -> SGPR);
// each thread runs TWO pair-circuits (pairs t and t+N/2, same geometry,
// images b and b+4096) with all 4 float4 loads hoisted to the top so load
// latency hides under the wave-uniform param block + first pair's compute.

#define N_PAIRS    (8192 * 98)     // pairs of adjacent 2x2 patches
#define HALF_PAIRS (N_PAIRS / 2)   // 401408 threads; 1568 blocks of 256
#define IMG_HALF_OFF (4096 * 784)  // float offset between pair t and t+HALF

typedef float v2f __attribute__((ext_vector_type(2)));

static __device__ __forceinline__ v2f splat(float v) { v2f r; r.x = v; r.y = v; return r; }
static __device__ __forceinline__ v2f vfma(v2f a, v2f b, v2f c) {
    return __builtin_elementwise_fma(a, b, c);
}
static __device__ __forceinline__ float uni(float v) {
    return __int_as_float(__builtin_amdgcn_readfirstlane(__float_as_int(v)));
}

// cos(x), sin(x) for x in [0,1): Taylor, err < 3e-5.
static __device__ __forceinline__ void trig01(v2f x, v2f& c, v2f& s) {
    v2f u = x * x;
    v2f sp = vfma(u, vfma(u, vfma(u, splat(-1.9841270e-4f), splat(8.3333338e-3f)),
                          splat(-1.6666667e-1f)), splat(1.0f));
    s = x * sp;
    c = vfma(u, vfma(u, vfma(u, vfma(u, splat(2.4801588e-5f), splat(-1.3888889e-3f)),
                             splat(4.1666668e-2f)), splat(-0.5f)), splat(1.0f));
}

// One packed pair of patches: row0/row1 pixels -> two float4 outputs.
static __device__ __forceinline__ void eval_pair(
    float4 row0, float4 row1,
    const float* __restrict__ cp, const float* __restrict__ sp,
    const float* __restrict__ K,
    float4& o0, float4& o1)
{
    v2f x0; x0.x = row0.x; x0.y = row0.z;
    v2f x1; x1.x = row0.y; x1.y = row0.w;
    v2f x2; x2.x = row1.x; x2.y = row1.z;
    v2f x3; x3.x = row1.y; x3.y = row1.w;

    v2f C0, S0, C1, S1, C2, S2, C3, S3, cx, sx;
    trig01(x0, cx, sx);
    C0 = cx * splat(cp[0]) - sx * splat(sp[0]); S0 = sx * splat(cp[0]) + cx * splat(sp[0]);
    trig01(x1, cx, sx);
    C1 = cx * splat(cp[1]) - sx * splat(sp[1]); S1 = sx * splat(cp[1]) + cx * splat(sp[1]);
    trig01(x2, cx, sx);
    C2 = cx * splat(cp[2]) - sx * splat(sp[2]); S2 = sx * splat(cp[2]) + cx * splat(sp[2]);
    trig01(x3, cx, sx);
    C3 = cx * splat(cp[3]) - sx * splat(sp[3]); S3 = sx * splat(cp[3]) + cx * splat(sp[3]);

    v2f C0C1 = C0 * C1, C0C2 = C0 * C2, C0C3 = C0 * C3;
    v2f C1C3 = C1 * C3, C2C3 = C2 * C3;
    v2f S0S1 = S0 * S1, S0S2 = S0 * S2, S0S3 = S0 * S3;
    v2f S1S2 = S1 * S2, S1S3 = S1 * S3, S2S3 = S2 * S3;
    v2f C2S3 = C2 * S3;

    v2f z0 =            splat(K[0])  * (C0 * C1C3);
    z0 = vfma(splat(K[1]),  S0S1 * C2S3, z0);
    z0 = vfma(splat(K[2]),  S1S2 * C3,   z0);
    z0 = vfma(splat(K[3]),  S0,          z0);

    v2f z1 =            splat(K[4])  * (C0 * C2C3);
    z1 = vfma(splat(K[5]),  S0S2, z1);

    v2f z2 =            splat(K[6])  * C1C3;
    z2 = vfma(splat(K[7]),  C0C3 * S1S2, z2);
    z2 = vfma(splat(K[8]),  S0S1 * C2,   z2);
    z2 = vfma(splat(K[9]),  S0S3,        z2);

    v2f z3 =            splat(K[10]) * C0C2;
    z3 = vfma(splat(K[11]), C1 * S2S3,        z3);
    z3 = vfma(splat(K[12]), C0 * S1S3,        z3);
    z3 = vfma(splat(K[13]), S0 * (C1 * C2C3), z3);
    z3 = vfma(splat(K[14]), C2S3,             z3);
    z3 = vfma(splat(K[15]), C0C1 * S2,        z3);
    z3 = vfma(splat(K[16]), S0S2 * C3,        z3);
    z3 = vfma(splat(K[17]), S1,               z3);

    o0 = make_float4(z0.x, z1.x, z2.x, z3.x);
    o1 = make_float4(z0.y, z1.y, z2.y, z3.y);
}

__global__ __launch_bounds__(256) void quanv_kernel(
    const float* __restrict__ x,       // (8192, 28, 28)
    const float* __restrict__ params,  // (2, 4)
    float* __restrict__ out)           // (8192, 784)
{
    int t = blockIdx.x * blockDim.x + threadIdx.x;   // [0, HALF_PAIRS)

    int b    = t / 98;
    int q    = t - b * 98;
    int r    = q / 7;
    int pcol = q - r * 7;

    // Hoisted loads for BOTH pairs (pair t in image b, pair t+HALF in b+4096).
    const float* pxA = x + b * 784 + (2 * r) * 28 + 4 * pcol;
    const float* pxB = pxA + IMG_HALF_OFF;
    float4 r0A = *reinterpret_cast<const float4*>(pxA);
    float4 r1A = *reinterpret_cast<const float4*>(pxA + 28);
    float4 r0B = *reinterpret_cast<const float4*>(pxB);
    float4 r1B = *reinterpret_cast<const float4*>(pxB + 28);

    // Wave-uniform parameter block (hides load latency); results in SGPRs.
    float cp[4], sp[4], cl[4], sl[4];
#pragma unroll
    for (int w = 0; w < 4; ++w) {
        float s_, c_;
        __sincosf(params[w], &s_, &c_);
        cp[w] = uni(c_); sp[w] = uni(s_);
        __sincosf(params[4 + w], &s_, &c_);
        cl[w] = uni(c_); sl[w] = uni(s_);
    }
    float K[18];
    K[0]  = uni( cl[1]*cl[2]*cl[3]);        // A
    K[1]  = uni(-cl[1]*cl[2]*sl[3]);        // B
    K[2]  = uni(-sl[1]*cl[2]*cl[3]);        // D
    K[3]  = uni(-sl[1]*sl[2]*sl[3]);        // E
    K[4]  = uni( cl[0]*cl[1]);              // F
    K[5]  = uni( sl[0]*sl[1]);              // G
    K[6]  = uni( cl[0]*cl[1]*cl[2]);        // H
    K[7]  = uni(-cl[0]*sl[1]*cl[2]);        // I
    K[8]  = uni(-sl[0]*cl[1]*cl[2]);        // J
    K[9]  = uni(-sl[0]*sl[1]*sl[2]);        // K
    K[10] = uni( cl[0]*cl[1]*cl[2]*cl[3]);  // L
    K[11] = uni(-cl[0]*cl[1]*sl[2]*cl[3]);  // M
    K[12] = uni( cl[0]*sl[1]*sl[2]*cl[3]);  // N
    K[13] = uni(-cl[0]*sl[1]*sl[2]*sl[3]);  // O
    K[14] = uni( sl[0]*cl[1]*cl[2]*sl[3]);  // P
    K[15] = uni(-sl[0]*cl[1]*sl[2]*sl[3]);  // Q
    K[16] = uni( sl[0]*sl[1]*cl[2]*cl[3]);  // R
    K[17] = uni( sl[0]*sl[1]*sl[2]*sl[3]);  // T

    float4 o0, o1;
    eval_pair(r0A, r1A, cp, sp, K, o0, o1);
    {
        float4* o = reinterpret_cast<float4*>(out + (size_t)t * 8);
        o[0] = o0; o[1] = o1;
    }
    eval_pair(r0B, r1B, cp, sp, K, o0, o1);
    {
        float4* o = reinterpret_cast<float4*>(out + ((size_t)t + HALF_PAIRS) * 8);
        o[0] = o0; o[1] = o1;
    }
}

extern "C" void kernel_launch(void* const* d_in, const int* in_sizes, int n_in,
                              void* d_out, int out_size, void* d_ws, size_t ws_size,
                              hipStream_t stream) {
    const float* x      = (const float*)d_in[0];  // (8192,28,28) f32
    const float* params = (const float*)d_in[1];  // (2,4) f32
    float* out          = (float*)d_out;          // (8192,784) f32

    const int block = 256;
    const int grid  = HALF_PAIRS / block;         // 1568, exact
    quanv_kernel<<<grid, block, 0, stream>>>(x, params, out);
}